// Round 3
// baseline (318.144 us; speedup 1.0000x reference)
//
#include <hip/hip_runtime.h>

// SpDepthWSepaConv3d: out[i,c] = bias[c] + sum_k mask[k,i] * features[pair_in[k,i],c] * weight[k,c]
// pair_out[k][i] == i whenever mask is set -> pure gather, no scatter/atomics.
//
// Device dtypes (established R0-R2): harness converts ALL integer inputs
// (incl. int64 pairs and bool mask) to int32 ("integer -> const int*").
//  - R1's int64 read of pair_in  -> garbage indices -> page fault (crash).
//  - R0's uchar read of pair_mask -> 3/4 of taps dropped -> absmax 1.96.
//
// Layout: one 64-lane wave per voxel, lane = channel. Mask branch is
// wave-uniform (no divergence); ~94% of taps are masked off (1.4% voxel
// density), so the branch skips both the pair_in load and the 256B gather.

#define KVOL 27

__global__ __launch_bounds__(256) void spconv_dw_kernel(
    const float* __restrict__ features,   // [n, 64]
    const float* __restrict__ weight,     // [27, 64]  (K,G,1,1)
    const float* __restrict__ bias,       // [64]
    const int* __restrict__ pair_in,      // [27, n] int32
    const int* __restrict__ pair_mask,    // [27, n] int32 (0/1)
    float* __restrict__ out,              // [n, 64]
    int n)
{
    const int vox = blockIdx.x * 4 + (threadIdx.x >> 6);
    const int c   = threadIdx.x & 63;
    if (vox >= n) return;

    float acc = bias[c];

    #pragma unroll 1
    for (int k = 0; k < KVOL; ++k) {
        // wave-uniform load: all 64 lanes of this wave share one voxel
        if (pair_mask[(size_t)k * n + vox]) {
            const int pin = pair_in[(size_t)k * n + vox];
            acc = fmaf(features[(size_t)pin * 64 + c], weight[k * 64 + c], acc);
        }
    }

    out[(size_t)vox * 64 + c] = acc;
}

extern "C" void kernel_launch(void* const* d_in, const int* in_sizes, int n_in,
                              void* d_out, int out_size, void* d_ws, size_t ws_size,
                              hipStream_t stream) {
    const float* features  = (const float*)d_in[0];
    const float* weight    = (const float*)d_in[1];
    const float* bias      = (const float*)d_in[2];
    const int* pair_in     = (const int*)d_in[3];
    // d_in[4] = pair_out — unused (pure gather, see kernel comment)
    const int* pair_mask   = (const int*)d_in[5];
    float* out             = (float*)d_out;

    const int n = in_sizes[0] / 64;          // N = 150000
    const int blocks = (n + 3) / 4;          // 4 voxels (waves) per 256-thread block

    spconv_dw_kernel<<<blocks, 256, 0, stream>>>(
        features, weight, bias, pair_in, pair_mask, out, n);
}

// Round 4
// 160.535 us; speedup vs baseline: 1.9818x; 1.9818x over previous
//
#include <hip/hip_runtime.h>

// SpDepthWSepaConv3d: out[i,c] = bias[c] + sum_k mask[k,i] * features[pair_in[k,i],c] * weight[k,c]
// pair_out[k][i] == i whenever mask is set -> pure gather, no scatter/atomics.
// Device dtypes (established R0-R2): all integer inputs are int32 on device.
//
// R3 structure: R2 was latency-bound (HBM 7%, VALU 10%, occ 88%) — 27
// serialized mask-load latencies per wave. Now lane c (c<27) loads tap c's
// mask and pair_in in ONE vector load each (27 taps in flight at once),
// __ballot forms the wave-uniform found set, and we loop over set bits
// (~1.35 avg) with __shfl broadcasting the gather index. Critical path:
// ~2 memory latencies instead of ~27.

#define KVOL 27

__global__ __launch_bounds__(256) void spconv_dw_kernel(
    const float* __restrict__ features,   // [n, 64]
    const float* __restrict__ weight,     // [27, 64]  (K,G,1,1)
    const float* __restrict__ bias,       // [64]
    const int* __restrict__ pair_in,      // [27, n] int32
    const int* __restrict__ pair_mask,    // [27, n] int32 (0/1)
    float* __restrict__ out,              // [n, 64]
    int n)
{
    const int vox = blockIdx.x * 4 + (threadIdx.x >> 6);
    const int c   = threadIdx.x & 63;
    if (vox >= n) return;

    // Lane-parallel tap metadata fetch: lane c handles tap k=c (c<27).
    int m = 0, pin_l = 0;
    if (c < KVOL) {
        const size_t off = (size_t)c * n + vox;
        m     = pair_mask[off];
        pin_l = pair_in[off];
    }
    // Wave-uniform found set; lanes 27..63 contribute 0 bits (m==0 there).
    unsigned long long found = __ballot(m != 0);

    float acc = bias[c];

    // ~1.35 iterations on average; trip count wave-uniform -> no divergence.
    while (found) {
        const int k = __ffsll(found) - 1;
        found &= found - 1;
        const int pin = __shfl(pin_l, k);                       // broadcast gather row
        acc = fmaf(features[(size_t)pin * 64 + c],              // 256B coalesced gather
                   weight[k * 64 + c], acc);
    }

    out[(size_t)vox * 64 + c] = acc;
}

extern "C" void kernel_launch(void* const* d_in, const int* in_sizes, int n_in,
                              void* d_out, int out_size, void* d_ws, size_t ws_size,
                              hipStream_t stream) {
    const float* features  = (const float*)d_in[0];
    const float* weight    = (const float*)d_in[1];
    const float* bias      = (const float*)d_in[2];
    const int* pair_in     = (const int*)d_in[3];
    // d_in[4] = pair_out — unused (pure gather, see kernel comment)
    const int* pair_mask   = (const int*)d_in[5];
    float* out             = (float*)d_out;

    const int n = in_sizes[0] / 64;          // N = 150000
    const int blocks = (n + 3) / 4;          // 4 voxels (waves) per 256-thread block

    spconv_dw_kernel<<<blocks, 256, 0, stream>>>(
        features, weight, bias, pair_in, pair_mask, out, n);
}

// Round 6
// 147.424 us; speedup vs baseline: 2.1580x; 1.0889x over previous
//
#include <hip/hip_runtime.h>

// SpDepthWSepaConv3d: out[i,c] = bias[c] + sum_k mask[k,i] * features[pair_in[k,i],c] * weight[k,c]
// Pure gather (pair_out[k][i]==i when mask set). All int inputs are int32 on device.
//
// R6 structure: R4 (proven correct incl. graph replay) + 4 voxels per wave.
// R4's FETCH=151.5 MB came from meta-line splitting: each 64B pair_mask/pair_in
// line covers 16 consecutive voxels, but R4 blocks held only 4 -> each line
// was fetched by ~4 different blocks on different (non-coherent) XCD L2s.
// Now one 256-thread block = 4 waves x 4 voxels = 16 consecutive voxels, so
// the 4 waves' same-line meta loads MSHR/L1-merge into one HBM fetch.
// R5's LDS+barrier+1024-block variant corrupted output under graph replay;
// this keeps the no-LDS, no-barrier, 256-block envelope.

#define KVOL 27
#define VPW  4    // voxels per wave
#define WPB  4    // waves per block -> 16 consecutive voxels per block

__global__ __launch_bounds__(256) void spconv_dw_kernel(
    const float* __restrict__ features,   // [n, 64]
    const float* __restrict__ weight,     // [27, 64]
    const float* __restrict__ bias,       // [64]
    const int* __restrict__ pair_in,      // [27, n] int32
    const int* __restrict__ pair_mask,    // [27, n] int32 (0/1)
    float* __restrict__ out,              // [n, 64]
    int n)
{
    const int t     = threadIdx.x;
    const int w     = t >> 6;                       // wave in block
    const int c     = t & 63;                       // channel / tap lane
    const int vbase = blockIdx.x * (VPW * WPB) + w * VPW;

    // Lane-parallel meta fetch for all 4 voxels up front: 8 independent loads
    // in flight at once. Lane c (c<27) holds tap c's mask/index per voxel.
    int m[VPW], p[VPW];
    #pragma unroll
    for (int s = 0; s < VPW; ++s) { m[s] = 0; p[s] = 0; }
    if (c < KVOL) {
        #pragma unroll
        for (int s = 0; s < VPW; ++s) {
            const int vox = vbase + s;
            if (vox < n) {
                const size_t off = (size_t)c * n + vox;
                m[s] = pair_mask[off];
                p[s] = pair_in[off];
            }
        }
    }

    const float b = bias[c];

    #pragma unroll
    for (int s = 0; s < VPW; ++s) {
        const int vox = vbase + s;                  // wave-uniform
        if (vox >= n) break;

        unsigned long long found = __ballot(m[s] != 0);  // wave-uniform tap set
        float acc = b;

        // ~1.35 iterations avg; trip count wave-uniform -> no divergence.
        while (found) {
            const int k = __ffsll(found) - 1;
            found &= found - 1;
            const int pin = __shfl(p[s], k);                 // broadcast gather row
            acc = fmaf(features[(size_t)pin * 64 + c],       // 256B coalesced gather
                       weight[k * 64 + c], acc);
        }

        out[(size_t)vox * 64 + c] = acc;
    }
}

extern "C" void kernel_launch(void* const* d_in, const int* in_sizes, int n_in,
                              void* d_out, int out_size, void* d_ws, size_t ws_size,
                              hipStream_t stream) {
    const float* features  = (const float*)d_in[0];
    const float* weight    = (const float*)d_in[1];
    const float* bias      = (const float*)d_in[2];
    const int* pair_in     = (const int*)d_in[3];
    // d_in[4] = pair_out — unused (pure gather)
    const int* pair_mask   = (const int*)d_in[5];
    float* out             = (float*)d_out;

    const int n = in_sizes[0] / 64;                       // N = 150000
    const int vpb = VPW * WPB;                            // 16 voxels per block
    const int blocks = (n + vpb - 1) / vpb;

    spconv_dw_kernel<<<blocks, 256, 0, stream>>>(
        features, weight, bias, pair_in, pair_mask, out, n);
}